// Round 1
// baseline (542.820 us; speedup 1.0000x reference)
//
#include <hip/hip_runtime.h>
#include <hip/hip_bf16.h>
#include <stdint.h>

// HMPNN layer: two NNConv(sum-agg)+sigmoid, concat, Linear(32,32), sigmoid.
// R3: z-outer-product: msg[e,:] = z[e,:] @ W', k=288, MFMA 16x16x32 bf16.
// R4: fuse metasteps a+b into ONE edge dispatch.
// R5: eliminate global atomics (WRITE_SIZE was 100MB write-through = 25.6M
//     scattered 4B atomic RMWs, the real bottleneck per rocprof):
//     - bucket_scatter: single pass, dst>>5 -> 1563 buckets/metastep of 32
//       nodes, fixed capacity slots (cap ~1024 >> max bucket ~600) so no
//       histogram/scan dispatches are needed.
//     - edge_mfma: one block per (bucket, metastep); accumulates into a
//       32x16 f32 LDS tile with LDS atomics, one coalesced 2KB store/block.
//     - attr fragment remapped to f = 8*q2 + t (contiguous): 8 scalar dword
//       loads -> 2 float4 loads (prep_w layout changed to match).
//     Predict: edge WRITE 100MB->6.6MB, edge dur 133->~45us, total ~210us.

#define NN 50000
#define EE 800000
#define NPB 32          // nodes per bucket
#define NB 1563         // ceil(NN / NPB)

typedef __attribute__((ext_vector_type(8))) short short8;
typedef __attribute__((ext_vector_type(4))) float f32x4;

union U8 { short8 v; unsigned int u[4]; };

__device__ __forceinline__ unsigned short f2bf_rne(float f) {
    union { float fl; unsigned int i; } v; v.fl = f;
    unsigned int x = v.i;
    x += 0x7FFFu + ((x >> 16) & 1u);
    return (unsigned short)(x >> 16);
}

__device__ __forceinline__ unsigned int pack2bf(float a, float b) {
    __hip_bfloat162 h = __float22bfloat162_rn(float2{a, b}); // x=low, y=high
    union { __hip_bfloat162 h2; unsigned int u; } c; c.h2 = h;
    return c.u;
}

// B-fragment for MFMA step t: wf[t*512 + lane*8 + j].
// t<8 : W'[f = 8*q2 + t][i = qb*8 + j][n = lane&15]   (q2=(lane>>5)&1, qb=(lane>>4)&1)
// t==8: bias row: q2==0 -> b_msg[i][n], q2==1 -> 0
__global__ void prep_w(const float* __restrict__ w_msg_a, const float* __restrict__ b_msg_a,
                       unsigned short* __restrict__ wf_a,
                       const float* __restrict__ w_msg_b, const float* __restrict__ b_msg_b,
                       unsigned short* __restrict__ wf_b) {
    const float* w_msg = blockIdx.x ? w_msg_b : w_msg_a;
    const float* b_msg = blockIdx.x ? b_msg_b : b_msg_a;
    unsigned short* wfrag = blockIdx.x ? wf_b : wf_a;
    for (int idx = threadIdx.x; idx < 9 * 64 * 8; idx += 256) {
        int j = idx & 7;
        int lane = (idx >> 3) & 63;
        int t = idx >> 9;
        int n = lane & 15;
        int qb = (lane >> 4) & 1;
        int q2 = (lane >> 5) & 1;
        int i = qb * 8 + j;
        int f = (t < 8) ? (8 * q2 + t) : (16 + q2);
        float v = (f < 16) ? w_msg[f * 256 + i * 16 + n]
                           : (f == 16 ? b_msg[i * 16 + n] : 0.f);
        wfrag[idx] = f2bf_rne(v);
    }
}

// Bucket edges by dst>>5. cnt must be zeroed first. col[(ms*NB+b)*cap + p] = e.
__global__ __launch_bounds__(256) void bucket_scatter(
    const int* __restrict__ ei_a, const int* __restrict__ ei_b,
    unsigned int* __restrict__ cnt, int* __restrict__ col, int cap)
{
    int idx = blockIdx.x * 256 + threadIdx.x;
    if (idx >= 2 * EE) return;
    int ms = idx >= EE;
    int e = ms ? idx - EE : idx;
    const int* ei = ms ? ei_b : ei_a;
    int dst = ei[EE + e];
    int b = dst >> 5;                       // NPB = 32
    unsigned int p = atomicAdd(&cnt[ms * NB + b], 1u);
    if (p < (unsigned int)cap)
        col[(size_t)(ms * NB + b) * cap + p] = e;
}

// One block per (bucket, metastep). 4 waves; wave handles chunks c, c+4, ...
// of 16 edges each. Per chunk: MFMA as before (lane m = edge slot in A rows,
// D[row=quad*4+r = edge slot][col=m = out dim]), then LDS atomicAdd into the
// bucket's 32x16 tile. Epilogue: one coalesced 2KB store (covers agg fully,
// so no agg memset is needed).
__global__ __launch_bounds__(256) void edge_mfma(
    const int* __restrict__ ei_a, const float* __restrict__ ea_a,
    const float* __restrict__ x_a, const unsigned short* __restrict__ wf_a,
    float* __restrict__ agg_a,
    const int* __restrict__ ei_b, const float* __restrict__ ea_b,
    const float* __restrict__ x_b, const unsigned short* __restrict__ wf_b,
    float* __restrict__ agg_b,
    const unsigned int* __restrict__ cnt, const int* __restrict__ col, int cap)
{
    int ms = blockIdx.x & 1;
    int b  = blockIdx.x >> 1;
    const int* __restrict__ ei     = ms ? ei_b : ei_a;
    const float* __restrict__ attr = ms ? ea_b : ea_a;
    const float* __restrict__ x    = ms ? x_b : x_a;
    const unsigned short* __restrict__ wfrag = ms ? wf_b : wf_a;
    float* __restrict__ agg = ms ? agg_b : agg_a;

    __shared__ float agg_lds[NPB * 16];     // 2 KB
    int tid = threadIdx.x;
    agg_lds[tid] = 0.f;
    agg_lds[tid + 256] = 0.f;
    __syncthreads();

    int lane = tid & 63, wid = tid >> 6;
    int m = lane & 15, quad = lane >> 4;
    int q2 = quad >> 1, qb = quad & 1;

    short8 bfr[9];
    #pragma unroll
    for (int t = 0; t < 9; ++t)
        bfr[t] = ((const short8*)wfrag)[t * 64 + lane];

    int cntb = (int)cnt[ms * NB + b];
    if (cntb > cap) cntb = cap;
    const int* __restrict__ colb = col + (size_t)(ms * NB + b) * cap;
    int nb0 = b * NPB;

    for (int c = wid; c * 16 < cntb; c += 4) {
        int base = c * 16;
        bool vm = (base + m) < cntb;
        int e = vm ? colb[base + m] : 0;
        int src = ei[e];
        int de  = ei[EE + e];               // dst of edge slot m

        const float4* xr = (const float4*)(x + (size_t)src * 16);
        float4 x0 = xr[qb * 2];
        float4 x1 = xr[qb * 2 + 1];
        float zf = vm ? 1.f : 0.f;
        float xh[8] = {x0.x * zf, x0.y * zf, x0.z * zf, x0.w * zf,
                       x1.x * zf, x1.y * zf, x1.z * zf, x1.w * zf};

        const float4* ar = (const float4*)(attr + (size_t)e * 16);
        float4 a0 = ar[q2 * 2];
        float4 a1 = ar[q2 * 2 + 1];
        float ah[8] = {a0.x, a0.y, a0.z, a0.w, a1.x, a1.y, a1.z, a1.w};

        f32x4 acc = {0.f, 0.f, 0.f, 0.f};
        #pragma unroll
        for (int t = 0; t < 8; ++t) {
            U8 a;
            #pragma unroll
            for (int jj = 0; jj < 4; ++jj)
                a.u[jj] = pack2bf(ah[t] * xh[2 * jj], ah[t] * xh[2 * jj + 1]);
            acc = __builtin_amdgcn_mfma_f32_16x16x32_bf16(a.v, bfr[t], acc, 0, 0, 0);
        }
        // t=8: bias row (q2==0: A = xj, q2==1: zero)
        U8 a8;
        #pragma unroll
        for (int jj = 0; jj < 4; ++jj)
            a8.u[jj] = (q2 == 0) ? pack2bf(xh[2 * jj], xh[2 * jj + 1]) : 0u;
        acc = __builtin_amdgcn_mfma_f32_16x16x32_bf16(a8.v, bfr[8], acc, 0, 0, 0);

        #pragma unroll
        for (int r = 0; r < 4; ++r) {
            int slot = base + quad * 4 + r;
            int d = __shfl(de, quad * 4 + r);   // dst of edge slot quad*4+r
            if (slot < cntb)
                atomicAdd(&agg_lds[(d - nb0) * 16 + m], acc[r]);
        }
    }
    __syncthreads();

    int i0 = tid, i1 = tid + 256;
    int n0 = nb0 + (i0 >> 4), n1 = nb0 + (i1 >> 4);
    if (n0 < NN) agg[(size_t)n0 * 16 + (i0 & 15)] = agg_lds[i0];
    if (n1 < NN) agg[(size_t)n1 * 16 + (i1 & 15)] = agg_lds[i1];
}

// out[n,d] = sigmoid( h @ w_lin + b_lin ), h = sigmoid(agg + x@root + bias)
__global__ __launch_bounds__(256) void finalize(
    const float* __restrict__ xind,
    const float* __restrict__ agg_a, const float* __restrict__ agg_b,
    const float* __restrict__ root_a, const float* __restrict__ bias_a,
    const float* __restrict__ root_b, const float* __restrict__ bias_b,
    const float* __restrict__ w_lin, const float* __restrict__ b_lin,
    float* __restrict__ out)
{
    int tid = threadIdx.x;
    int n = blockIdx.x * 8 + (tid >> 5);
    if (n >= NN) return;
    int d = tid & 31;
    int lane = tid & 63;
    int gb32 = lane & ~31;

    float xv = xind[n * 16 + (d & 15)];

    int j = d & 15;
    const float* root = (d < 16) ? root_a : root_b;
    const float* bias = (d < 16) ? bias_a : bias_b;
    const float* agg  = (d < 16) ? agg_a  : agg_b;

    float acc = agg[n * 16 + j] + bias[j];
    #pragma unroll
    for (int i = 0; i < 16; ++i) {
        float xiv = __shfl(xv, gb32 + i);
        acc += xiv * root[i * 16 + j];
    }
    float h = 1.f / (1.f + __expf(-acc));

    float acc2 = b_lin[d];
    #pragma unroll
    for (int jj = 0; jj < 32; ++jj) {
        float hj = __shfl(h, gb32 + jj);
        acc2 += hj * w_lin[jj * 32 + d];
    }
    out[(size_t)n * 32 + d] = 1.f / (1.f + __expf(-acc2));
}

extern "C" void kernel_launch(void* const* d_in, const int* in_sizes, int n_in,
                              void* d_out, int out_size, void* d_ws, size_t ws_size,
                              hipStream_t stream) {
    (void)in_sizes; (void)n_in; (void)out_size;
    const float* x_indivi = (const float*)d_in[0];
    const float* x_src_a  = (const float*)d_in[1];
    const float* x_src_b  = (const float*)d_in[2];
    const int*   ei_a     = (const int*)d_in[3];
    const int*   ei_b     = (const int*)d_in[4];
    const float* ea_a     = (const float*)d_in[5];
    const float* ea_b     = (const float*)d_in[6];
    const float* w_msg_a  = (const float*)d_in[7];
    const float* b_msg_a  = (const float*)d_in[8];
    const float* root_a   = (const float*)d_in[9];
    const float* bias_a   = (const float*)d_in[10];
    const float* w_msg_b  = (const float*)d_in[11];
    const float* b_msg_b  = (const float*)d_in[12];
    const float* root_b   = (const float*)d_in[13];
    const float* bias_b   = (const float*)d_in[14];
    const float* w_lin    = (const float*)d_in[15];
    const float* b_lin    = (const float*)d_in[16];
    float* out = (float*)d_out;

    char* ws = (char*)d_ws;
    size_t off = 0;
    auto alloc = [&](size_t bytes) -> void* {
        void* p = ws + off;
        off += (bytes + 255) & ~(size_t)255;
        return p;
    };
    unsigned short* wf_a = (unsigned short*)alloc(9 * 64 * 8 * 2);   // 9216 B
    unsigned short* wf_b = (unsigned short*)alloc(9 * 64 * 8 * 2);
    unsigned int*   cnt  = (unsigned int*)alloc(2 * NB * 4);         // 12.5 KB
    float* agg_a = (float*)alloc((size_t)NN * 16 * 4);               // 3.2 MB
    float* agg_b = (float*)alloc((size_t)NN * 16 * 4);
    // remaining workspace -> col slots. mean bucket count 512, sigma ~22,
    // max over 3126 buckets ~600; cap 1024 gives huge margin. Overflow is
    // guarded (dropped) in scatter so memory safety never depends on cap.
    size_t avail = ws_size > off ? ws_size - off : 0;
    int cap = (int)(avail / (2 * (size_t)NB * 4));
    if (cap > 1024) cap = 1024;
    int* col = (int*)(ws + off);

    hipMemsetAsync(cnt, 0, 2 * NB * 4, stream);
    prep_w<<<2, 256, 0, stream>>>(w_msg_a, b_msg_a, wf_a, w_msg_b, b_msg_b, wf_b);

    bucket_scatter<<<(2 * EE + 255) / 256, 256, 0, stream>>>(ei_a, ei_b, cnt, col, cap);

    edge_mfma<<<2 * NB, 256, 0, stream>>>(ei_a, ea_a, x_src_a, wf_a, agg_a,
                                          ei_b, ea_b, x_src_b, wf_b, agg_b,
                                          cnt, col, cap);

    finalize<<<(NN + 7) / 8, 256, 0, stream>>>(
        x_indivi, agg_a, agg_b, root_a, bias_a, root_b, bias_b, w_lin, b_lin, out);
}

// Round 3
// 457.017 us; speedup vs baseline: 1.1877x; 1.1877x over previous
//
#include <hip/hip_runtime.h>
#include <hip/hip_bf16.h>
#include <stdint.h>

// HMPNN layer: two NNConv(sum-agg)+sigmoid, concat, Linear(32,32), sigmoid.
// R3: z-outer-product: msg[e,:] = z[e,:] @ W', k=288, MFMA 16x16x32 bf16.
// R4: fuse metasteps a+b into ONE edge dispatch.
// R5: bucket-by-dst (dst>>5) + LDS aggregation; killed 100MB of global-atomic
//     write-through in edge_mfma. BUT scatter = 219us: 1.6M RETURNING atomics
//     on 3126 counters = 512 serialized RMWs/address x ~430ns = the wall.
// R6: 16 sub-counters/bucket (512 -> 32 serial RMWs), col carries
//     {src, e|dlocal<<20}, LDS compaction, cnt-zero folded into prep_w.
//     (R6 bench was an infra failure - container died pre-run; no signal.)
// R7: resubmit R6 + overflow-safety: scatter overflow edges spill to a global
//     list, folded into agg by an exact-f32 cleanup kernel (expected 0 edges
//     at CAP=64 ~ 5.7 sigma) - correctness independent of ws_size.

#define NN 50000
#define EE 800000
#define NPB 32          // nodes per bucket
#define NB 1563         // ceil(NN / NPB)
#define NSUB 16         // sub-counters per bucket (contention divider)
#define CAP 64          // slots per sub-bucket: mean 32, sigma 5.7
#define OVF_CAP (1 << 19)   // 512K spill entries (2 MB)

typedef __attribute__((ext_vector_type(8))) short short8;
typedef __attribute__((ext_vector_type(4))) float f32x4;

union U8 { short8 v; unsigned int u[4]; };

__device__ __forceinline__ unsigned short f2bf_rne(float f) {
    union { float fl; unsigned int i; } v; v.fl = f;
    unsigned int x = v.i;
    x += 0x7FFFu + ((x >> 16) & 1u);
    return (unsigned short)(x >> 16);
}

__device__ __forceinline__ unsigned int pack2bf(float a, float b) {
    __hip_bfloat162 h = __float22bfloat162_rn(float2{a, b}); // x=low, y=high
    union { __hip_bfloat162 h2; unsigned int u; } c; c.h2 = h;
    return c.u;
}

// B-fragment for MFMA step t: wf[t*512 + lane*8 + j].
// t<8 : W'[f = 8*q2 + t][i = qb*8 + j][n = lane&15]
// t==8: bias row: q2==0 -> b_msg[i][n], q2==1 -> 0
// blocks 0,1: build wf_a / wf_b.  blocks >=2: zero cnt[] (+ ovf counter).
__global__ void prep_w(const float* __restrict__ w_msg_a, const float* __restrict__ b_msg_a,
                       unsigned short* __restrict__ wf_a,
                       const float* __restrict__ w_msg_b, const float* __restrict__ b_msg_b,
                       unsigned short* __restrict__ wf_b,
                       unsigned int* __restrict__ cnt, int cnt_words) {
    if (blockIdx.x >= 2) {
        int idx = (blockIdx.x - 2) * 256 + threadIdx.x;
        if (idx < cnt_words) cnt[idx] = 0u;
        return;
    }
    const float* w_msg = blockIdx.x ? w_msg_b : w_msg_a;
    const float* b_msg = blockIdx.x ? b_msg_b : b_msg_a;
    unsigned short* wfrag = blockIdx.x ? wf_b : wf_a;
    for (int idx = threadIdx.x; idx < 9 * 64 * 8; idx += 256) {
        int j = idx & 7;
        int lane = (idx >> 3) & 63;
        int t = idx >> 9;
        int n = lane & 15;
        int qb = (lane >> 4) & 1;
        int q2 = (lane >> 5) & 1;
        int i = qb * 8 + j;
        int f = (t < 8) ? (8 * q2 + t) : (16 + q2);
        float v = (f < 16) ? w_msg[f * 256 + i * 16 + n]
                           : (f == 16 ? b_msg[i * 16 + n] : 0.f);
        wfrag[idx] = f2bf_rne(v);
    }
}

// Bucket edges by dst>>5 into NSUB independent sub-lists per bucket.
// col[((ms*NB+b)*NSUB + c)*cap + p] = {src, e | dlocal<<20}.
// Overflow (p >= cap): spill e|ms<<20 to ovf list (handled exactly later).
__global__ __launch_bounds__(256) void bucket_scatter(
    const int* __restrict__ ei_a, const int* __restrict__ ei_b,
    unsigned int* __restrict__ cnt, uint2* __restrict__ col, int cap,
    unsigned int* __restrict__ ovf_cnt, unsigned int* __restrict__ ovf)
{
    int idx = blockIdx.x * 256 + threadIdx.x;
    if (idx >= 2 * EE) return;
    int ms = idx >= EE;
    int e = ms ? idx - EE : idx;
    const int* ei = ms ? ei_b : ei_a;
    int dst = ei[EE + e];
    int src = ei[e];
    int b = dst >> 5;                         // NPB = 32
    int c = e & (NSUB - 1);
    int bc = (ms * NB + b) * NSUB + c;
    unsigned int p = atomicAdd(&cnt[bc], 1u);
    if (p < (unsigned int)cap) {
        col[(size_t)bc * cap + p] =
            uint2{(unsigned int)src, (unsigned int)(e | ((dst & (NPB - 1)) << 20))};
    } else {
        unsigned int q = atomicAdd(ovf_cnt, 1u);
        if (q < OVF_CAP) ovf[q] = (unsigned int)(e | (ms << 20));
    }
}

// One block per (bucket, metastep). Compact the NSUB sub-lists into one LDS
// list, then 4 waves MFMA over 16-edge chunks, LDS-atomic into the bucket's
// 32x16 f32 tile, one coalesced 2KB store (covers agg fully -> no memset).
__global__ __launch_bounds__(256) void edge_mfma(
    const float* __restrict__ ea_a, const float* __restrict__ x_a,
    const unsigned short* __restrict__ wf_a, float* __restrict__ agg_a,
    const float* __restrict__ ea_b, const float* __restrict__ x_b,
    const unsigned short* __restrict__ wf_b, float* __restrict__ agg_b,
    const unsigned int* __restrict__ cnt, const uint2* __restrict__ col, int cap)
{
    int ms = blockIdx.x & 1;
    int b  = blockIdx.x >> 1;
    const float* __restrict__ attr = ms ? ea_b : ea_a;
    const float* __restrict__ x    = ms ? x_b : x_a;
    const unsigned short* __restrict__ wfrag = ms ? wf_b : wf_a;
    float* __restrict__ agg = ms ? agg_b : agg_a;

    __shared__ float agg_lds[NPB * 16];       // 2 KB
    __shared__ uint2 list[NSUB * CAP];        // 8 KB
    __shared__ int s_cc[NSUB];

    int tid = threadIdx.x;
    agg_lds[tid] = 0.f;
    agg_lds[tid + 256] = 0.f;

    int base16 = (ms * NB + b) * NSUB;
    if (tid < NSUB) {
        int v = (int)cnt[base16 + tid];
        s_cc[tid] = v < cap ? v : cap;
    }
    __syncthreads();

    // compact sub-lists -> contiguous LDS list
    const uint2* __restrict__ colb = col + (size_t)base16 * cap;
    int tot = 0;
    #pragma unroll
    for (int c = 0; c < NSUB; ++c) {
        int cc = s_cc[c];
        for (int i = tid; i < cc; i += 256)
            list[tot + i] = colb[c * cap + i];
        tot += cc;
    }
    __syncthreads();

    int lane = tid & 63, wid = tid >> 6;
    int m = lane & 15, quad = lane >> 4;
    int q2 = quad >> 1, qb = quad & 1;

    short8 bfr[9];
    #pragma unroll
    for (int t = 0; t < 9; ++t)
        bfr[t] = ((const short8*)wfrag)[t * 64 + lane];

    int nchunks = (tot + 15) >> 4;
    for (int ch = wid; ch < nchunks; ch += 4) {
        int base = ch * 16;
        int slot = base + m;
        bool vm = slot < tot;
        uint2 pe = vm ? list[slot] : uint2{0u, 0u};
        int src = (int)pe.x;
        int e   = (int)(pe.y & 0xFFFFFu);
        int dl  = (int)((pe.y >> 20) & (NPB - 1));

        const float4* xr = (const float4*)(x + (size_t)src * 16);
        float4 x0 = xr[qb * 2];
        float4 x1 = xr[qb * 2 + 1];
        float zf = vm ? 1.f : 0.f;
        float xh[8] = {x0.x * zf, x0.y * zf, x0.z * zf, x0.w * zf,
                       x1.x * zf, x1.y * zf, x1.z * zf, x1.w * zf};

        const float4* ar = (const float4*)(attr + (size_t)e * 16);
        float4 a0 = ar[q2 * 2];
        float4 a1 = ar[q2 * 2 + 1];
        float ah[8] = {a0.x, a0.y, a0.z, a0.w, a1.x, a1.y, a1.z, a1.w};

        f32x4 acc = {0.f, 0.f, 0.f, 0.f};
        #pragma unroll
        for (int t = 0; t < 8; ++t) {
            U8 a;
            #pragma unroll
            for (int jj = 0; jj < 4; ++jj)
                a.u[jj] = pack2bf(ah[t] * xh[2 * jj], ah[t] * xh[2 * jj + 1]);
            acc = __builtin_amdgcn_mfma_f32_16x16x32_bf16(a.v, bfr[t], acc, 0, 0, 0);
        }
        // t=8: bias row (q2==0: A = xj, q2==1: zero)
        U8 a8;
        #pragma unroll
        for (int jj = 0; jj < 4; ++jj)
            a8.u[jj] = (q2 == 0) ? pack2bf(xh[2 * jj], xh[2 * jj + 1]) : 0u;
        acc = __builtin_amdgcn_mfma_f32_16x16x32_bf16(a8.v, bfr[8], acc, 0, 0, 0);

        #pragma unroll
        for (int r = 0; r < 4; ++r) {
            int s2 = base + quad * 4 + r;
            int dlr = __shfl(dl, quad * 4 + r);   // dlocal of edge slot quad*4+r
            if (s2 < tot)
                atomicAdd(&agg_lds[dlr * 16 + m], acc[r]);
        }
    }
    __syncthreads();

    int nb0 = b * NPB;
    int i0 = tid, i1 = tid + 256;
    int n0 = nb0 + (i0 >> 4), n1 = nb0 + (i1 >> 4);
    if (n0 < NN) agg[(size_t)n0 * 16 + (i0 & 15)] = agg_lds[i0];
    if (n1 < NN) agg[(size_t)n1 * 16 + (i1 & 15)] = agg_lds[i1];
}

// Exact-f32 fallback for spilled edges (expected 0). 16 threads per edge
// (one per output dim o): msg[o] = sum_i xj[i]*(b_msg[i][o] +
// sum_f attr[f]*w_msg[f][i][o]); global atomicAdd into agg.
__global__ __launch_bounds__(256) void ovf_cleanup(
    const int* __restrict__ ei_a, const float* __restrict__ ea_a,
    const float* __restrict__ x_a,
    const float* __restrict__ w_msg_a, const float* __restrict__ b_msg_a,
    float* __restrict__ agg_a,
    const int* __restrict__ ei_b, const float* __restrict__ ea_b,
    const float* __restrict__ x_b,
    const float* __restrict__ w_msg_b, const float* __restrict__ b_msg_b,
    float* __restrict__ agg_b,
    const unsigned int* __restrict__ ovf_cnt, const unsigned int* __restrict__ ovf)
{
    unsigned int n = *ovf_cnt;
    if (n > OVF_CAP) n = OVF_CAP;
    int total = (int)n * 16;
    for (int idx = blockIdx.x * 256 + threadIdx.x; idx < total;
         idx += gridDim.x * 256) {
        int o = idx & 15;
        unsigned int rec = ovf[idx >> 4];
        int e = (int)(rec & 0xFFFFFu);
        int ms = (int)((rec >> 20) & 1u);
        const int* ei = ms ? ei_b : ei_a;
        const float* attr = ms ? ea_b : ea_a;
        const float* x = ms ? x_b : x_a;
        const float* w_msg = ms ? w_msg_b : w_msg_a;
        const float* b_msg = ms ? b_msg_b : b_msg_a;
        float* agg = ms ? agg_b : agg_a;
        int src = ei[e], dst = ei[EE + e];
        const float* ar = attr + (size_t)e * 16;
        const float* xj = x + (size_t)src * 16;
        float acc = 0.f;
        #pragma unroll
        for (int i = 0; i < 16; ++i) {
            float we = b_msg[i * 16 + o];
            #pragma unroll
            for (int f = 0; f < 16; ++f)
                we += ar[f] * w_msg[f * 256 + i * 16 + o];
            acc += xj[i] * we;
        }
        atomicAdd(&agg[(size_t)dst * 16 + o], acc);
    }
}

// out[n,d] = sigmoid( h @ w_lin + b_lin ), h = sigmoid(agg + x@root + bias)
__global__ __launch_bounds__(256) void finalize(
    const float* __restrict__ xind,
    const float* __restrict__ agg_a, const float* __restrict__ agg_b,
    const float* __restrict__ root_a, const float* __restrict__ bias_a,
    const float* __restrict__ root_b, const float* __restrict__ bias_b,
    const float* __restrict__ w_lin, const float* __restrict__ b_lin,
    float* __restrict__ out)
{
    int tid = threadIdx.x;
    int n = blockIdx.x * 8 + (tid >> 5);
    if (n >= NN) return;
    int d = tid & 31;
    int lane = tid & 63;
    int gb32 = lane & ~31;

    float xv = xind[n * 16 + (d & 15)];

    int j = d & 15;
    const float* root = (d < 16) ? root_a : root_b;
    const float* bias = (d < 16) ? bias_a : bias_b;
    const float* agg  = (d < 16) ? agg_a  : agg_b;

    float acc = agg[n * 16 + j] + bias[j];
    #pragma unroll
    for (int i = 0; i < 16; ++i) {
        float xiv = __shfl(xv, gb32 + i);
        acc += xiv * root[i * 16 + j];
    }
    float h = 1.f / (1.f + __expf(-acc));

    float acc2 = b_lin[d];
    #pragma unroll
    for (int jj = 0; jj < 32; ++jj) {
        float hj = __shfl(h, gb32 + jj);
        acc2 += hj * w_lin[jj * 32 + d];
    }
    out[(size_t)n * 32 + d] = 1.f / (1.f + __expf(-acc2));
}

extern "C" void kernel_launch(void* const* d_in, const int* in_sizes, int n_in,
                              void* d_out, int out_size, void* d_ws, size_t ws_size,
                              hipStream_t stream) {
    (void)in_sizes; (void)n_in; (void)out_size;
    const float* x_indivi = (const float*)d_in[0];
    const float* x_src_a  = (const float*)d_in[1];
    const float* x_src_b  = (const float*)d_in[2];
    const int*   ei_a     = (const int*)d_in[3];
    const int*   ei_b     = (const int*)d_in[4];
    const float* ea_a     = (const float*)d_in[5];
    const float* ea_b     = (const float*)d_in[6];
    const float* w_msg_a  = (const float*)d_in[7];
    const float* b_msg_a  = (const float*)d_in[8];
    const float* root_a   = (const float*)d_in[9];
    const float* bias_a   = (const float*)d_in[10];
    const float* w_msg_b  = (const float*)d_in[11];
    const float* b_msg_b  = (const float*)d_in[12];
    const float* root_b   = (const float*)d_in[13];
    const float* bias_b   = (const float*)d_in[14];
    const float* w_lin    = (const float*)d_in[15];
    const float* b_lin    = (const float*)d_in[16];
    float* out = (float*)d_out;

    char* ws = (char*)d_ws;
    size_t off = 0;
    auto alloc = [&](size_t bytes) -> void* {
        void* p = ws + off;
        off += (bytes + 255) & ~(size_t)255;
        return p;
    };
    unsigned short* wf_a = (unsigned short*)alloc(9 * 64 * 8 * 2);    // 9216 B
    unsigned short* wf_b = (unsigned short*)alloc(9 * 64 * 8 * 2);
    const int nsub_words = 2 * NB * NSUB;                             // 50016
    const int cnt_words = nsub_words + 1;                             // + ovf_cnt
    unsigned int* cnt = (unsigned int*)alloc(cnt_words * 4);          // 200 KB
    unsigned int* ovf_cnt = cnt + nsub_words;
    unsigned int* ovf = (unsigned int*)alloc(OVF_CAP * 4);            // 2 MB
    float* agg_a = (float*)alloc((size_t)NN * 16 * 4);                // 3.2 MB
    float* agg_b = (float*)alloc((size_t)NN * 16 * 4);
    // col: 2*NB*NSUB sub-lists x cap slots x 8B. CAP=64 -> 25.6 MB.
    size_t avail = ws_size > off ? ws_size - off : 0;
    int cap = (int)(avail / ((size_t)nsub_words * 8));
    if (cap > CAP) cap = CAP;
    uint2* col = (uint2*)(ws + off);

    prep_w<<<2 + (cnt_words + 255) / 256, 256, 0, stream>>>(
        w_msg_a, b_msg_a, wf_a, w_msg_b, b_msg_b, wf_b, cnt, cnt_words);

    bucket_scatter<<<(2 * EE + 255) / 256, 256, 0, stream>>>(
        ei_a, ei_b, cnt, col, cap, ovf_cnt, ovf);

    edge_mfma<<<2 * NB, 256, 0, stream>>>(ea_a, x_src_a, wf_a, agg_a,
                                          ea_b, x_src_b, wf_b, agg_b,
                                          cnt, col, cap);

    ovf_cleanup<<<64, 256, 0, stream>>>(
        ei_a, ea_a, x_src_a, w_msg_a, b_msg_a, agg_a,
        ei_b, ea_b, x_src_b, w_msg_b, b_msg_b, agg_b, ovf_cnt, ovf);

    finalize<<<(NN + 7) / 8, 256, 0, stream>>>(
        x_indivi, agg_a, agg_b, root_a, bias_a, root_b, bias_b, w_lin, b_lin, out);
}

// Round 4
// 433.677 us; speedup vs baseline: 1.2517x; 1.0538x over previous
//
#include <hip/hip_runtime.h>
#include <hip/hip_bf16.h>
#include <stdint.h>

// HMPNN layer: two NNConv(sum-agg)+sigmoid, concat, Linear(32,32), sigmoid.
// R3: z-outer-product: msg[e,:] = z[e,:] @ W', k=288, MFMA 16x16x32 bf16.
// R4: fuse metasteps a+b into ONE edge dispatch. edge=133us, atomic-bound.
// R5: bucket-by-dst (dst>>5) + LDS agg. scatter=219us: 512 serial RMWs/addr.
// R6/R7: 16 sub-counters + LDS compaction + ovf spill. Result: edge WRITE
//     100MB->6.25MB (good) but edge 133->186us (latency-bound, grid only
//     12.5k waves vs 8192 slots, occ 38%, nothing busy) and scatter only
//     ~2x better (~115us inferred): sub-counters of a bucket share ONE 64B
//     line -> per-LINE RMW chain still 512 deep.
// R8: (1) pad counters to 64B lines (chain 512->32/line),
//     (2) split each (bucket,ms) into 2 half-blocks -> 6252 blocks, separate
//         agg copies summed in finalize (no atomics),
//     (3) depth-2 software pipeline in the chunk loop.
//     Predict: scatter ~30us, edge 186->~85us, total ~260us.

#define NN 50000
#define EE 800000
#define NPB 32          // nodes per bucket
#define NB 1563         // ceil(NN / NPB)
#define NSUB 16         // sub-counters per bucket (contention divider)
#define CAP 64          // slots per sub-bucket: mean 32, sigma 5.7
#define CNT_PAD 16      // words per counter -> one 64B line each
#define OVF_CAP (1 << 19)   // 512K spill entries (2 MB)

typedef __attribute__((ext_vector_type(8))) short short8;
typedef __attribute__((ext_vector_type(4))) float f32x4;

union U8 { short8 v; unsigned int u[4]; };

__device__ __forceinline__ unsigned short f2bf_rne(float f) {
    union { float fl; unsigned int i; } v; v.fl = f;
    unsigned int x = v.i;
    x += 0x7FFFu + ((x >> 16) & 1u);
    return (unsigned short)(x >> 16);
}

__device__ __forceinline__ unsigned int pack2bf(float a, float b) {
    __hip_bfloat162 h = __float22bfloat162_rn(float2{a, b}); // x=low, y=high
    union { __hip_bfloat162 h2; unsigned int u; } c; c.h2 = h;
    return c.u;
}

// B-fragment for MFMA step t: wf[t*512 + lane*8 + j].
// t<8 : W'[f = 8*q2 + t][i = qb*8 + j][n = lane&15]
// t==8: bias row: q2==0 -> b_msg[i][n], q2==1 -> 0
// blocks 0,1: build wf_a / wf_b.  blocks >=2: zero cnt[] (padded) + ovf_cnt.
__global__ void prep_w(const float* __restrict__ w_msg_a, const float* __restrict__ b_msg_a,
                       unsigned short* __restrict__ wf_a,
                       const float* __restrict__ w_msg_b, const float* __restrict__ b_msg_b,
                       unsigned short* __restrict__ wf_b,
                       unsigned int* __restrict__ cnt, int cnt_zero_words) {
    if (blockIdx.x >= 2) {
        int idx = (blockIdx.x - 2) * 256 + threadIdx.x;
        if (idx < cnt_zero_words) cnt[idx] = 0u;
        return;
    }
    const float* w_msg = blockIdx.x ? w_msg_b : w_msg_a;
    const float* b_msg = blockIdx.x ? b_msg_b : b_msg_a;
    unsigned short* wfrag = blockIdx.x ? wf_b : wf_a;
    for (int idx = threadIdx.x; idx < 9 * 64 * 8; idx += 256) {
        int j = idx & 7;
        int lane = (idx >> 3) & 63;
        int t = idx >> 9;
        int n = lane & 15;
        int qb = (lane >> 4) & 1;
        int q2 = (lane >> 5) & 1;
        int i = qb * 8 + j;
        int f = (t < 8) ? (8 * q2 + t) : (16 + q2);
        float v = (f < 16) ? w_msg[f * 256 + i * 16 + n]
                           : (f == 16 ? b_msg[i * 16 + n] : 0.f);
        wfrag[idx] = f2bf_rne(v);
    }
}

// Bucket edges by dst>>5 into NSUB sub-lists per bucket. Counters padded to
// 64B (CNT_PAD words) so RMW chains don't share cache lines.
// col[((ms*NB+b)*NSUB + c)*cap + p] = {src, e | dlocal<<20}.
__global__ __launch_bounds__(256) void bucket_scatter(
    const int* __restrict__ ei_a, const int* __restrict__ ei_b,
    unsigned int* __restrict__ cnt, uint2* __restrict__ col, int cap,
    unsigned int* __restrict__ ovf_cnt, unsigned int* __restrict__ ovf)
{
    int idx = blockIdx.x * 256 + threadIdx.x;
    if (idx >= 2 * EE) return;
    int ms = idx >= EE;
    int e = ms ? idx - EE : idx;
    const int* ei = ms ? ei_b : ei_a;
    int dst = ei[EE + e];
    int src = ei[e];
    int b = dst >> 5;                         // NPB = 32
    int c = e & (NSUB - 1);
    int bc = (ms * NB + b) * NSUB + c;
    unsigned int p = atomicAdd(&cnt[(size_t)bc * CNT_PAD], 1u);
    if (p < (unsigned int)cap) {
        col[(size_t)bc * cap + p] =
            uint2{(unsigned int)src, (unsigned int)(e | ((dst & (NPB - 1)) << 20))};
    } else {
        unsigned int q = atomicAdd(ovf_cnt, 1u);
        if (q < OVF_CAP) ovf[q] = (unsigned int)(e | (ms << 20));
    }
}

// One block per (bucket, metastep, half). Each half-block compacts ITS HALF
// of the bucket's edge list into LDS, MFMAs 16-edge chunks with a depth-2
// software pipeline, LDS-atomics into a 32x16 tile, then stores the tile to
// its own agg copy (finalize sums the two copies; no global atomics).
__global__ __launch_bounds__(256) void edge_mfma(
    const float* __restrict__ ea_a, const float* __restrict__ x_a,
    const unsigned short* __restrict__ wf_a,
    float* __restrict__ agg_a0, float* __restrict__ agg_a1,
    const float* __restrict__ ea_b, const float* __restrict__ x_b,
    const unsigned short* __restrict__ wf_b,
    float* __restrict__ agg_b0, float* __restrict__ agg_b1,
    const unsigned int* __restrict__ cnt, const uint2* __restrict__ col, int cap)
{
    int bid = blockIdx.x;
    int b  = bid >> 2;
    int ms = (bid >> 1) & 1;
    int h  = bid & 1;
    const float* __restrict__ attr = ms ? ea_b : ea_a;
    const float* __restrict__ x    = ms ? x_b : x_a;
    const unsigned short* __restrict__ wfrag = ms ? wf_b : wf_a;
    float* __restrict__ agg = ms ? (h ? agg_b1 : agg_b0) : (h ? agg_a1 : agg_a0);

    __shared__ float agg_lds[NPB * 16];       // 2 KB
    __shared__ uint2 list[512];               // 4 KB (half-list <= 512)
    __shared__ int s_cc[NSUB];

    int tid = threadIdx.x;
    agg_lds[tid] = 0.f;
    agg_lds[tid + 256] = 0.f;

    int base16 = (ms * NB + b) * NSUB;
    if (tid < NSUB) {
        int v = (int)cnt[(size_t)(base16 + tid) * CNT_PAD];
        s_cc[tid] = v < cap ? v : cap;
    }
    __syncthreads();

    // exclusive prefix (16 values, per-thread regs, static indexing only)
    int off[NSUB + 1];
    off[0] = 0;
    #pragma unroll
    for (int c = 0; c < NSUB; ++c) off[c + 1] = off[c] + s_cc[c];
    int tot = off[NSUB];
    int hs = ((tot + 31) >> 5) << 4;          // half, rounded to 16
    if (hs > tot) hs = tot;
    int s0 = h ? hs : 0;
    int s1 = h ? tot : hs;
    int len = s1 - s0;

    // compact this half's slots [s0,s1) -> contiguous LDS list
    const uint2* __restrict__ colb = col + (size_t)base16 * cap;
    for (int i = tid; i < len; i += 256) {
        int g = s0 + i;
        int c = 0, oc = 0;
        #pragma unroll
        for (int k = 1; k < NSUB; ++k)
            if (off[k] <= g) { c = k; oc = off[k]; }
        list[i] = colb[c * cap + (g - oc)];
    }
    __syncthreads();

    int lane = tid & 63, wid = tid >> 6;
    int m = lane & 15, quad = lane >> 4;
    int q2 = quad >> 1, qb = quad & 1;

    short8 bfr[9];
    #pragma unroll
    for (int t = 0; t < 9; ++t)
        bfr[t] = ((const short8*)wfrag)[t * 64 + lane];

    int nchunks = (len + 15) >> 4;

    // depth-2 software pipeline over this wave's chunks (wid, wid+4, ...)
    int ch = wid;
    bool vmC = false;
    uint2 peC = {0u, 0u};
    float4 xA = {0,0,0,0}, xB = {0,0,0,0}, aA = {0,0,0,0}, aB = {0,0,0,0};
    if (ch < nchunks) {
        int slot = ch * 16 + m;
        vmC = slot < len;
        peC = vmC ? list[slot] : uint2{0u, 0u};
        const float4* xr = (const float4*)(x + (size_t)peC.x * 16);
        xA = xr[qb * 2]; xB = xr[qb * 2 + 1];
        const float4* ar = (const float4*)(attr + (size_t)(peC.y & 0xFFFFFu) * 16);
        aA = ar[q2 * 2]; aB = ar[q2 * 2 + 1];
    }
    while (ch < nchunks) {
        int nx = ch + 4;
        bool vmN = false;
        uint2 peN = {0u, 0u};
        float4 xA2 = {0,0,0,0}, xB2 = {0,0,0,0}, aA2 = {0,0,0,0}, aB2 = {0,0,0,0};
        if (nx < nchunks) {
            int slot = nx * 16 + m;
            vmN = slot < len;
            peN = vmN ? list[slot] : uint2{0u, 0u};
            const float4* xr = (const float4*)(x + (size_t)peN.x * 16);
            xA2 = xr[qb * 2]; xB2 = xr[qb * 2 + 1];
            const float4* ar = (const float4*)(attr + (size_t)(peN.y & 0xFFFFFu) * 16);
            aA2 = ar[q2 * 2]; aB2 = ar[q2 * 2 + 1];
        }

        // compute current chunk
        float zf = vmC ? 1.f : 0.f;
        float xh[8] = {xA.x * zf, xA.y * zf, xA.z * zf, xA.w * zf,
                       xB.x * zf, xB.y * zf, xB.z * zf, xB.w * zf};
        float ah[8] = {aA.x, aA.y, aA.z, aA.w, aB.x, aB.y, aB.z, aB.w};

        f32x4 acc = {0.f, 0.f, 0.f, 0.f};
        #pragma unroll
        for (int t = 0; t < 8; ++t) {
            U8 a;
            #pragma unroll
            for (int jj = 0; jj < 4; ++jj)
                a.u[jj] = pack2bf(ah[t] * xh[2 * jj], ah[t] * xh[2 * jj + 1]);
            acc = __builtin_amdgcn_mfma_f32_16x16x32_bf16(a.v, bfr[t], acc, 0, 0, 0);
        }
        U8 a8;
        #pragma unroll
        for (int jj = 0; jj < 4; ++jj)
            a8.u[jj] = (q2 == 0) ? pack2bf(xh[2 * jj], xh[2 * jj + 1]) : 0u;
        acc = __builtin_amdgcn_mfma_f32_16x16x32_bf16(a8.v, bfr[8], acc, 0, 0, 0);

        int base = ch * 16;
        int dl = (int)((peC.y >> 20) & (NPB - 1));
        #pragma unroll
        for (int r = 0; r < 4; ++r) {
            int s2 = base + quad * 4 + r;
            int dlr = __shfl(dl, quad * 4 + r);   // dlocal of edge slot quad*4+r
            if (s2 < len)
                atomicAdd(&agg_lds[dlr * 16 + m], acc[r]);
        }

        // rotate pipeline
        ch = nx;
        vmC = vmN; peC = peN;
        xA = xA2; xB = xB2; aA = aA2; aB = aB2;
    }
    __syncthreads();

    int nb0 = b * NPB;
    int i0 = tid, i1 = tid + 256;
    int n0 = nb0 + (i0 >> 4), n1 = nb0 + (i1 >> 4);
    if (n0 < NN) agg[(size_t)n0 * 16 + (i0 & 15)] = agg_lds[i0];
    if (n1 < NN) agg[(size_t)n1 * 16 + (i1 & 15)] = agg_lds[i1];
}

// Exact-f32 fallback for spilled edges (expected 0). Adds into copy 0
// (runs after edge_mfma's plain stores).
__global__ __launch_bounds__(256) void ovf_cleanup(
    const int* __restrict__ ei_a, const float* __restrict__ ea_a,
    const float* __restrict__ x_a,
    const float* __restrict__ w_msg_a, const float* __restrict__ b_msg_a,
    float* __restrict__ agg_a0,
    const int* __restrict__ ei_b, const float* __restrict__ ea_b,
    const float* __restrict__ x_b,
    const float* __restrict__ w_msg_b, const float* __restrict__ b_msg_b,
    float* __restrict__ agg_b0,
    const unsigned int* __restrict__ ovf_cnt, const unsigned int* __restrict__ ovf)
{
    unsigned int n = *ovf_cnt;
    if (n > OVF_CAP) n = OVF_CAP;
    int total = (int)n * 16;
    for (int idx = blockIdx.x * 256 + threadIdx.x; idx < total;
         idx += gridDim.x * 256) {
        int o = idx & 15;
        unsigned int rec = ovf[idx >> 4];
        int e = (int)(rec & 0xFFFFFu);
        int ms = (int)((rec >> 20) & 1u);
        const int* ei = ms ? ei_b : ei_a;
        const float* attr = ms ? ea_b : ea_a;
        const float* x = ms ? x_b : x_a;
        const float* w_msg = ms ? w_msg_b : w_msg_a;
        const float* b_msg = ms ? b_msg_b : b_msg_a;
        float* agg = ms ? agg_b0 : agg_a0;
        int src = ei[e], dst = ei[EE + e];
        const float* ar = attr + (size_t)e * 16;
        const float* xj = x + (size_t)src * 16;
        float acc = 0.f;
        #pragma unroll
        for (int i = 0; i < 16; ++i) {
            float we = b_msg[i * 16 + o];
            #pragma unroll
            for (int f = 0; f < 16; ++f)
                we += ar[f] * w_msg[f * 256 + i * 16 + o];
            acc += xj[i] * we;
        }
        atomicAdd(&agg[(size_t)dst * 16 + o], acc);
    }
}

// out[n,d] = sigmoid( h @ w_lin + b_lin ), h = sigmoid(agg0+agg1 + x@root + bias)
__global__ __launch_bounds__(256) void finalize(
    const float* __restrict__ xind,
    const float* __restrict__ agg_a0, const float* __restrict__ agg_a1,
    const float* __restrict__ agg_b0, const float* __restrict__ agg_b1,
    const float* __restrict__ root_a, const float* __restrict__ bias_a,
    const float* __restrict__ root_b, const float* __restrict__ bias_b,
    const float* __restrict__ w_lin, const float* __restrict__ b_lin,
    float* __restrict__ out)
{
    int tid = threadIdx.x;
    int n = blockIdx.x * 8 + (tid >> 5);
    if (n >= NN) return;
    int d = tid & 31;
    int lane = tid & 63;
    int gb32 = lane & ~31;

    float xv = xind[n * 16 + (d & 15)];

    int j = d & 15;
    const float* root = (d < 16) ? root_a : root_b;
    const float* bias = (d < 16) ? bias_a : bias_b;
    const float* agg0 = (d < 16) ? agg_a0 : agg_b0;
    const float* agg1 = (d < 16) ? agg_a1 : agg_b1;

    float acc = agg0[n * 16 + j] + agg1[n * 16 + j] + bias[j];
    #pragma unroll
    for (int i = 0; i < 16; ++i) {
        float xiv = __shfl(xv, gb32 + i);
        acc += xiv * root[i * 16 + j];
    }
    float h = 1.f / (1.f + __expf(-acc));

    float acc2 = b_lin[d];
    #pragma unroll
    for (int jj = 0; jj < 32; ++jj) {
        float hj = __shfl(h, gb32 + jj);
        acc2 += hj * w_lin[jj * 32 + d];
    }
    out[(size_t)n * 32 + d] = 1.f / (1.f + __expf(-acc2));
}

extern "C" void kernel_launch(void* const* d_in, const int* in_sizes, int n_in,
                              void* d_out, int out_size, void* d_ws, size_t ws_size,
                              hipStream_t stream) {
    (void)in_sizes; (void)n_in; (void)out_size;
    const float* x_indivi = (const float*)d_in[0];
    const float* x_src_a  = (const float*)d_in[1];
    const float* x_src_b  = (const float*)d_in[2];
    const int*   ei_a     = (const int*)d_in[3];
    const int*   ei_b     = (const int*)d_in[4];
    const float* ea_a     = (const float*)d_in[5];
    const float* ea_b     = (const float*)d_in[6];
    const float* w_msg_a  = (const float*)d_in[7];
    const float* b_msg_a  = (const float*)d_in[8];
    const float* root_a   = (const float*)d_in[9];
    const float* bias_a   = (const float*)d_in[10];
    const float* w_msg_b  = (const float*)d_in[11];
    const float* b_msg_b  = (const float*)d_in[12];
    const float* root_b   = (const float*)d_in[13];
    const float* bias_b   = (const float*)d_in[14];
    const float* w_lin    = (const float*)d_in[15];
    const float* b_lin    = (const float*)d_in[16];
    float* out = (float*)d_out;

    char* ws = (char*)d_ws;
    size_t off = 0;
    auto alloc = [&](size_t bytes) -> void* {
        void* p = ws + off;
        off += (bytes + 255) & ~(size_t)255;
        return p;
    };
    unsigned short* wf_a = (unsigned short*)alloc(9 * 64 * 8 * 2);    // 9216 B
    unsigned short* wf_b = (unsigned short*)alloc(9 * 64 * 8 * 2);
    const int nsub_words = 2 * NB * NSUB;                             // 50016
    const int cnt_zero_words = nsub_words * CNT_PAD + 1;              // + ovf_cnt
    unsigned int* cnt = (unsigned int*)alloc((size_t)cnt_zero_words * 4); // 3.2 MB
    unsigned int* ovf_cnt = cnt + (size_t)nsub_words * CNT_PAD;
    unsigned int* ovf = (unsigned int*)alloc(OVF_CAP * 4);            // 2 MB
    float* agg_a0 = (float*)alloc((size_t)NN * 16 * 4);               // 3.2 MB x4
    float* agg_a1 = (float*)alloc((size_t)NN * 16 * 4);
    float* agg_b0 = (float*)alloc((size_t)NN * 16 * 4);
    float* agg_b1 = (float*)alloc((size_t)NN * 16 * 4);
    // col: 2*NB*NSUB sub-lists x cap slots x 8B. CAP=64 -> 25.6 MB.
    size_t avail = ws_size > off ? ws_size - off : 0;
    int cap = (int)(avail / ((size_t)nsub_words * 8));
    if (cap > CAP) cap = CAP;
    uint2* col = (uint2*)(ws + off);

    prep_w<<<2 + (cnt_zero_words + 255) / 256, 256, 0, stream>>>(
        w_msg_a, b_msg_a, wf_a, w_msg_b, b_msg_b, wf_b, cnt, cnt_zero_words);

    bucket_scatter<<<(2 * EE + 255) / 256, 256, 0, stream>>>(
        ei_a, ei_b, cnt, col, cap, ovf_cnt, ovf);

    edge_mfma<<<4 * NB, 256, 0, stream>>>(
        ea_a, x_src_a, wf_a, agg_a0, agg_a1,
        ea_b, x_src_b, wf_b, agg_b0, agg_b1,
        cnt, col, cap);

    ovf_cleanup<<<64, 256, 0, stream>>>(
        ei_a, ea_a, x_src_a, w_msg_a, b_msg_a, agg_a0,
        ei_b, ea_b, x_src_b, w_msg_b, b_msg_b, agg_b0, ovf_cnt, ovf);

    finalize<<<(NN + 7) / 8, 256, 0, stream>>>(
        x_indivi, agg_a0, agg_a1, agg_b0, agg_b1,
        root_a, bias_a, root_b, bias_b, w_lin, b_lin, out);
}

// Round 5
// 371.617 us; speedup vs baseline: 1.4607x; 1.1670x over previous
//
#include <hip/hip_runtime.h>
#include <hip/hip_bf16.h>
#include <stdint.h>

// HMPNN layer: two NNConv(sum-agg)+sigmoid, concat, Linear(32,32), sigmoid.
// R3: z-outer-product: msg[e,:] = z[e,:] @ W', k=288, MFMA 16x16x32 bf16.
// R4: fused edge dispatch, global atomics: edge 133us (atomic-throughput).
// R5-R8: fine buckets (32 nodes) + scatter. Learned: (a) scatter is bound by
//     SCATTERED 8B STORES (~365GB/s effective, 1 record/line), NOT atomic
//     chains (padding didn't help); (b) 32-node buckets make edge_mfma
//     latency-bound (154MB random 64B gathers, tiny blocks, occ 40%).
// R9: COARSE bins (512 nodes, 98/ms) + per-(bin,ablock) fixed regions:
//     - bin_scatter: 8192-edge blocks, LDS histogram ranks, records written
//       in ~672B contiguous runs (95% line utilization), ZERO global atomics.
//     - edge_mfma: 1 block per (bin,ms,sub): 512x16 f32 LDS tile (32KB),
//       edge runs read CONTIGUOUSLY, depth-2 pipeline, partial tiles
//       (plain stores) summed in finalize.
//     Predict: scatter ~12us, edge ~45us, total ~150us.

#define NN 50000
#define EE 800000
#define SHIFT 9                 // 512 nodes per bin
#define CBIN 512
#define BPM 98                  // bins per metastep = ceil(50000/512)
#define ABM 98                  // A-blocks per metastep = ceil(800000/8192)
#define CAPB 144                // per-(bin,ablock) capacity: mean 84, sigma 9.1
#define SUBS 2                  // aggregation sub-blocks per bin
#define OVF_CAP (1 << 19)       // 512K spill entries (2 MB)

typedef __attribute__((ext_vector_type(8))) short short8;
typedef __attribute__((ext_vector_type(4))) float f32x4;

union U8 { short8 v; unsigned int u[4]; };

__device__ __forceinline__ unsigned short f2bf_rne(float f) {
    union { float fl; unsigned int i; } v; v.fl = f;
    unsigned int x = v.i;
    x += 0x7FFFu + ((x >> 16) & 1u);
    return (unsigned short)(x >> 16);
}

__device__ __forceinline__ unsigned int pack2bf(float a, float b) {
    __hip_bfloat162 h = __float22bfloat162_rn(float2{a, b}); // x=low, y=high
    union { __hip_bfloat162 h2; unsigned int u; } c; c.h2 = h;
    return c.u;
}

// B-fragment for MFMA step t: wf[t*512 + lane*8 + j].
// t<8 : W'[f = 8*q2 + t][i = qb*8 + j][n = lane&15]
// t==8: bias row: q2==0 -> b_msg[i][n], q2==1 -> 0
// block 2: zero ovf_cnt.
__global__ void prep_w(const float* __restrict__ w_msg_a, const float* __restrict__ b_msg_a,
                       unsigned short* __restrict__ wf_a,
                       const float* __restrict__ w_msg_b, const float* __restrict__ b_msg_b,
                       unsigned short* __restrict__ wf_b,
                       unsigned int* __restrict__ ovf_cnt) {
    if (blockIdx.x >= 2) {
        if (threadIdx.x == 0) *ovf_cnt = 0u;
        return;
    }
    const float* w_msg = blockIdx.x ? w_msg_b : w_msg_a;
    const float* b_msg = blockIdx.x ? b_msg_b : b_msg_a;
    unsigned short* wfrag = blockIdx.x ? wf_b : wf_a;
    for (int idx = threadIdx.x; idx < 9 * 64 * 8; idx += 256) {
        int j = idx & 7;
        int lane = (idx >> 3) & 63;
        int t = idx >> 9;
        int n = lane & 15;
        int qb = (lane >> 4) & 1;
        int q2 = (lane >> 5) & 1;
        int i = qb * 8 + j;
        int f = (t < 8) ? (8 * q2 + t) : (16 + q2);
        float v = (f < 16) ? w_msg[f * 256 + i * 16 + n]
                           : (f == 16 ? b_msg[i * 16 + n] : 0.f);
        wfrag[idx] = f2bf_rne(v);
    }
}

// 8192 contiguous edges per block. LDS histogram assigns per-(block,bin)
// ranks; records land in fixed region ((ms*BPM+bin)*ABM+ablk)*CAPB as
// contiguous ~84-record runs. cntA[(ms*BPM+bin)*ABM+ablk] = raw count.
// No global atomics (except rare ovf spill).
__global__ __launch_bounds__(1024) void bin_scatter(
    const int* __restrict__ ei_a, const int* __restrict__ ei_b,
    unsigned int* __restrict__ cntA, uint2* __restrict__ col,
    unsigned int* __restrict__ ovf_cnt, unsigned int* __restrict__ ovf)
{
    int bid = blockIdx.x;
    int ms = bid >= ABM;
    int ablk = ms ? bid - ABM : bid;
    const int* __restrict__ ei = ms ? ei_b : ei_a;

    __shared__ unsigned int lcnt[BPM];
    int tid = threadIdx.x;
    if (tid < BPM) lcnt[tid] = 0u;
    __syncthreads();

    int e0 = ablk * 8192;
    int srcv[8], dstv[8];
    unsigned int rr[8];
    #pragma unroll
    for (int k = 0; k < 8; ++k) {
        int e = e0 + k * 1024 + tid;
        bool v = e < EE;
        int dst = v ? ei[EE + e] : 0;
        int src = v ? ei[e] : 0;
        srcv[k] = src; dstv[k] = dst;
        rr[k] = v ? atomicAdd(&lcnt[dst >> SHIFT], 1u) : 0xFFFFFFFFu;
    }
    __syncthreads();
    if (tid < BPM)
        cntA[(size_t)(ms * BPM + tid) * ABM + ablk] = lcnt[tid];

    #pragma unroll
    for (int k = 0; k < 8; ++k) {
        int e = e0 + k * 1024 + tid;
        if (e >= EE) continue;
        int dst = dstv[k];
        int bin = dst >> SHIFT;
        unsigned int r = rr[k];
        if (r < CAPB) {
            size_t pos = ((size_t)(ms * BPM + bin) * ABM + ablk) * CAPB + r;
            col[pos] = uint2{(unsigned int)srcv[k],
                             (unsigned int)(e | ((dst & (CBIN - 1)) << 20))};
        } else {
            unsigned int q = atomicAdd(ovf_cnt, 1u);
            if (q < OVF_CAP) ovf[q] = (unsigned int)(e | (ms << 20));
        }
    }
}

// One block per (bin, ms, sub). 512x16 f32 LDS tile covers the whole bin.
// 8 slices (SUBS*4 waves) own ablks sl, sl+8, ... ; each run is contiguous
// in col. Depth-2 pipeline over 16-edge chunks; LDS atomics into the tile;
// epilogue stores the 32KB partial tile (summed with the other sub in
// finalize). No global atomics.
__global__ __launch_bounds__(256) void edge_mfma(
    const float* __restrict__ ea_a, const float* __restrict__ x_a,
    const unsigned short* __restrict__ wf_a,
    const float* __restrict__ ea_b, const float* __restrict__ x_b,
    const unsigned short* __restrict__ wf_b,
    const unsigned int* __restrict__ cntA, const uint2* __restrict__ col,
    float* __restrict__ partial)
{
    int bid = blockIdx.x;
    int bin = bid >> 2;
    int ms  = (bid >> 1) & 1;
    int sub = bid & 1;
    const float* __restrict__ attr = ms ? ea_b : ea_a;
    const float* __restrict__ x    = ms ? x_b : x_a;
    const unsigned short* __restrict__ wfrag = ms ? wf_b : wf_a;

    __shared__ float tile[CBIN * 16];     // 32 KB
    __shared__ int s_len[ABM];

    int tid = threadIdx.x;
    for (int i = tid; i < CBIN * 16; i += 256) tile[i] = 0.f;
    size_t cbase = (size_t)(ms * BPM + bin) * ABM;
    for (int i = tid; i < ABM; i += 256) {
        int v = (int)cntA[cbase + i];
        s_len[i] = v < CAPB ? v : CAPB;
    }
    __syncthreads();

    int lane = tid & 63, wid = tid >> 6;
    int m = lane & 15, quad = lane >> 4;
    int q2 = quad >> 1, qb = quad & 1;

    short8 bfr[9];
    #pragma unroll
    for (int t = 0; t < 9; ++t)
        bfr[t] = ((const short8*)wfrag)[t * 64 + lane];

    const uint2* __restrict__ colb = col + cbase * CAPB;
    int sl = sub * 4 + wid;               // slice 0..7 across the 2 sub-blocks

    // descriptor: (g = ablk, ch = chunk-in-run, len = run length)
    int gC = sl, chC = 0, lenC = (gC < ABM) ? s_len[gC] : 0;
    while (gC < ABM && chC * 16 >= lenC) {
        gC += 8; chC = 0; lenC = (gC < ABM) ? s_len[gC] : 0;
    }

    bool vmC = false;
    uint2 peC = {0u, 0u};
    float4 xA = {0,0,0,0}, xB = {0,0,0,0}, aA = {0,0,0,0}, aB = {0,0,0,0};
    if (gC < ABM) {
        int slot = chC * 16 + m;
        vmC = slot < lenC;
        peC = vmC ? colb[(size_t)gC * CAPB + slot] : uint2{0u, 0u};
        const float4* xr = (const float4*)(x + (size_t)peC.x * 16);
        xA = xr[qb * 2]; xB = xr[qb * 2 + 1];
        const float4* ar = (const float4*)(attr + (size_t)(peC.y & 0xFFFFFu) * 16);
        aA = ar[q2 * 2]; aB = ar[q2 * 2 + 1];
    }

    while (gC < ABM) {
        // advance descriptor to next chunk of this slice
        int gN = gC, chN = chC + 1, lenN = lenC;
        while (gN < ABM && chN * 16 >= lenN) {
            gN += 8; chN = 0; lenN = (gN < ABM) ? s_len[gN] : 0;
        }
        // prefetch next
        bool vmN = false;
        uint2 peN = {0u, 0u};
        float4 xA2 = {0,0,0,0}, xB2 = {0,0,0,0}, aA2 = {0,0,0,0}, aB2 = {0,0,0,0};
        if (gN < ABM) {
            int slot = chN * 16 + m;
            vmN = slot < lenN;
            peN = vmN ? colb[(size_t)gN * CAPB + slot] : uint2{0u, 0u};
            const float4* xr = (const float4*)(x + (size_t)peN.x * 16);
            xA2 = xr[qb * 2]; xB2 = xr[qb * 2 + 1];
            const float4* ar = (const float4*)(attr + (size_t)(peN.y & 0xFFFFFu) * 16);
            aA2 = ar[q2 * 2]; aB2 = ar[q2 * 2 + 1];
        }

        // compute current chunk
        float zf = vmC ? 1.f : 0.f;
        float xh[8] = {xA.x * zf, xA.y * zf, xA.z * zf, xA.w * zf,
                       xB.x * zf, xB.y * zf, xB.z * zf, xB.w * zf};
        float ah[8] = {aA.x, aA.y, aA.z, aA.w, aB.x, aB.y, aB.z, aB.w};

        f32x4 acc = {0.f, 0.f, 0.f, 0.f};
        #pragma unroll
        for (int t = 0; t < 8; ++t) {
            U8 a;
            #pragma unroll
            for (int jj = 0; jj < 4; ++jj)
                a.u[jj] = pack2bf(ah[t] * xh[2 * jj], ah[t] * xh[2 * jj + 1]);
            acc = __builtin_amdgcn_mfma_f32_16x16x32_bf16(a.v, bfr[t], acc, 0, 0, 0);
        }
        U8 a8;
        #pragma unroll
        for (int jj = 0; jj < 4; ++jj)
            a8.u[jj] = (q2 == 0) ? pack2bf(xh[2 * jj], xh[2 * jj + 1]) : 0u;
        acc = __builtin_amdgcn_mfma_f32_16x16x32_bf16(a8.v, bfr[8], acc, 0, 0, 0);

        int dl = (int)((peC.y >> 20) & (CBIN - 1));
        #pragma unroll
        for (int r = 0; r < 4; ++r) {
            int s2 = chC * 16 + quad * 4 + r;
            int dlr = __shfl(dl, quad * 4 + r);   // dlocal of edge slot quad*4+r
            if (s2 < lenC)
                atomicAdd(&tile[dlr * 16 + m], acc[r]);
        }

        // rotate pipeline
        gC = gN; chC = chN; lenC = lenN;
        vmC = vmN; peC = peN;
        xA = xA2; xB = xB2; aA = aA2; aB = aB2;
    }
    __syncthreads();

    float* __restrict__ pt =
        partial + ((size_t)(ms * BPM + bin) * SUBS + sub) * (CBIN * 16);
    for (int i = tid; i < CBIN * 16; i += 256) pt[i] = tile[i];
}

// Exact-f32 fallback for spilled edges (expected 0): atomicAdd into the
// sub-0 partial tile (runs after edge_mfma's plain stores).
__global__ __launch_bounds__(256) void ovf_cleanup(
    const int* __restrict__ ei_a, const float* __restrict__ ea_a,
    const float* __restrict__ x_a,
    const float* __restrict__ w_msg_a, const float* __restrict__ b_msg_a,
    const int* __restrict__ ei_b, const float* __restrict__ ea_b,
    const float* __restrict__ x_b,
    const float* __restrict__ w_msg_b, const float* __restrict__ b_msg_b,
    float* __restrict__ partial,
    const unsigned int* __restrict__ ovf_cnt, const unsigned int* __restrict__ ovf)
{
    unsigned int n = *ovf_cnt;
    if (n > OVF_CAP) n = OVF_CAP;
    int total = (int)n * 16;
    for (int idx = blockIdx.x * 256 + threadIdx.x; idx < total;
         idx += gridDim.x * 256) {
        int o = idx & 15;
        unsigned int rec = ovf[idx >> 4];
        int e = (int)(rec & 0xFFFFFu);
        int ms = (int)((rec >> 20) & 1u);
        const int* ei = ms ? ei_b : ei_a;
        const float* attr = ms ? ea_b : ea_a;
        const float* x = ms ? x_b : x_a;
        const float* w_msg = ms ? w_msg_b : w_msg_a;
        const float* b_msg = ms ? b_msg_b : b_msg_a;
        int src = ei[e], dst = ei[EE + e];
        const float* ar = attr + (size_t)e * 16;
        const float* xj = x + (size_t)src * 16;
        float acc = 0.f;
        #pragma unroll
        for (int i = 0; i < 16; ++i) {
            float we = b_msg[i * 16 + o];
            #pragma unroll
            for (int f = 0; f < 16; ++f)
                we += ar[f] * w_msg[f * 256 + i * 16 + o];
            acc += xj[i] * we;
        }
        size_t slot = ((size_t)(ms * BPM + (dst >> SHIFT)) * SUBS) * (CBIN * 16)
                      + (size_t)(dst & (CBIN - 1)) * 16 + o;
        atomicAdd(&partial[slot], acc);
    }
}

// out[n,d] = sigmoid( h @ w_lin + b_lin ),
// h = sigmoid( sum_subs partial + x@root + bias )
__global__ __launch_bounds__(256) void finalize(
    const float* __restrict__ xind, const float* __restrict__ partial,
    const float* __restrict__ root_a, const float* __restrict__ bias_a,
    const float* __restrict__ root_b, const float* __restrict__ bias_b,
    const float* __restrict__ w_lin, const float* __restrict__ b_lin,
    float* __restrict__ out)
{
    int tid = threadIdx.x;
    int n = blockIdx.x * 8 + (tid >> 5);
    if (n >= NN) return;
    int d = tid & 31;
    int lane = tid & 63;
    int gb32 = lane & ~31;

    float xv = xind[n * 16 + (d & 15)];

    int j = d & 15;
    int ms = (d < 16) ? 0 : 1;
    const float* root = ms ? root_b : root_a;
    const float* bias = ms ? bias_b : bias_a;

    int bin = n >> SHIFT, dl = n & (CBIN - 1);
    const float* pa = partial + ((size_t)(ms * BPM + bin) * SUBS) * (CBIN * 16)
                      + (size_t)dl * 16 + j;
    float acc = pa[0] + pa[CBIN * 16] + bias[j];
    #pragma unroll
    for (int i = 0; i < 16; ++i) {
        float xiv = __shfl(xv, gb32 + i);
        acc += xiv * root[i * 16 + j];
    }
    float h = 1.f / (1.f + __expf(-acc));

    float acc2 = b_lin[d];
    #pragma unroll
    for (int jj = 0; jj < 32; ++jj) {
        float hj = __shfl(h, gb32 + jj);
        acc2 += hj * w_lin[jj * 32 + d];
    }
    out[(size_t)n * 32 + d] = 1.f / (1.f + __expf(-acc2));
}

extern "C" void kernel_launch(void* const* d_in, const int* in_sizes, int n_in,
                              void* d_out, int out_size, void* d_ws, size_t ws_size,
                              hipStream_t stream) {
    (void)in_sizes; (void)n_in; (void)out_size; (void)ws_size;
    const float* x_indivi = (const float*)d_in[0];
    const float* x_src_a  = (const float*)d_in[1];
    const float* x_src_b  = (const float*)d_in[2];
    const int*   ei_a     = (const int*)d_in[3];
    const int*   ei_b     = (const int*)d_in[4];
    const float* ea_a     = (const float*)d_in[5];
    const float* ea_b     = (const float*)d_in[6];
    const float* w_msg_a  = (const float*)d_in[7];
    const float* b_msg_a  = (const float*)d_in[8];
    const float* root_a   = (const float*)d_in[9];
    const float* bias_a   = (const float*)d_in[10];
    const float* w_msg_b  = (const float*)d_in[11];
    const float* b_msg_b  = (const float*)d_in[12];
    const float* root_b   = (const float*)d_in[13];
    const float* bias_b   = (const float*)d_in[14];
    const float* w_lin    = (const float*)d_in[15];
    const float* b_lin    = (const float*)d_in[16];
    float* out = (float*)d_out;

    char* ws = (char*)d_ws;
    size_t off = 0;
    auto alloc = [&](size_t bytes) -> void* {
        void* p = ws + off;
        off += (bytes + 255) & ~(size_t)255;
        return p;
    };
    unsigned short* wf_a = (unsigned short*)alloc(9 * 64 * 8 * 2);        // 9216 B
    unsigned short* wf_b = (unsigned short*)alloc(9 * 64 * 8 * 2);
    unsigned int* cntA   = (unsigned int*)alloc((size_t)2 * BPM * ABM * 4);  // 77 KB
    unsigned int* ovf_cnt = (unsigned int*)alloc(256);
    unsigned int* ovf    = (unsigned int*)alloc((size_t)OVF_CAP * 4);     // 2 MB
    uint2* col = (uint2*)alloc((size_t)2 * BPM * ABM * CAPB * 8);         // 22.1 MB
    float* partial = (float*)alloc((size_t)2 * BPM * SUBS * CBIN * 16 * 4); // 12.8 MB

    prep_w<<<3, 256, 0, stream>>>(w_msg_a, b_msg_a, wf_a,
                                  w_msg_b, b_msg_b, wf_b, ovf_cnt);

    bin_scatter<<<2 * ABM, 1024, 0, stream>>>(ei_a, ei_b, cntA, col, ovf_cnt, ovf);

    edge_mfma<<<BPM * 2 * SUBS, 256, 0, stream>>>(
        ea_a, x_src_a, wf_a, ea_b, x_src_b, wf_b, cntA, col, partial);

    ovf_cleanup<<<64, 256, 0, stream>>>(
        ei_a, ea_a, x_src_a, w_msg_a, b_msg_a,
        ei_b, ea_b, x_src_b, w_msg_b, b_msg_b, partial, ovf_cnt, ovf);

    finalize<<<(NN + 7) / 8, 256, 0, stream>>>(
        x_indivi, partial, root_a, bias_a, root_b, bias_b, w_lin, b_lin, out);
}